// Round 11
// baseline (214.793 us; speedup 1.0000x reference)
//
#include <hip/hip_runtime.h>

typedef __bf16 bf16x8 __attribute__((ext_vector_type(8)));
typedef __bf16 bf16x4 __attribute__((ext_vector_type(4)));
typedef float  f32x4  __attribute__((ext_vector_type(4)));

// Shapes: B=64, C=256, T=128, V=25, K=3, G=4, Cg=64, dk=16
// ws: xm f32 @0 | afull bf16 @1,638,400 | wcb bf16 @2,031,616

// ---- Kernel 1: temporal mean (pure stream, deterministic tree-sum) [R5/R7/R9-verified] ----
__global__ __launch_bounds__(256)
void k_tmean4(const float* __restrict__ x, float* __restrict__ xm)
{
    const int bid = blockIdx.x;            // b*128 + c2
    const int b = bid >> 7, c2 = bid & 127;
    const int tid = threadIdx.x;
    const int c_loc = tid >> 7, r = tid & 127;

    __shared__ float xpart[2][25][5][4];   // 4 KB

    if (r < 125) {
        const float* base = x + (size_t)(b * 256 + c2 * 2 + c_loc) * 3200;
        f32x4 acc = {0.f, 0.f, 0.f, 0.f};
#pragma unroll
        for (int i = 0; i < 7; ++i) {
            const int q = r + 125 * i;
            if (q < 800) {
                f32x4 v4 = *(const f32x4*)(base + q * 4);   // 16B-aligned
                acc += v4;
            }
        }
        const int vq = r % 25, jg = r / 25;
        *(f32x4*)(&xpart[c_loc][vq][jg][0]) = acc;
    }
    __syncthreads();
    if (tid < 50) {
        const int cl = tid / 25, v = tid - cl * 25;
        float s = 0.f;
#pragma unroll
        for (int e = 0; e < 4; ++e) {
            const int vq = (((v - e + 25) % 25) * 19) % 25;  // 4*vq == v-e (mod 25)
#pragma unroll
            for (int j = 0; j < 5; ++j) s += xpart[cl][vq][j][e];
        }
        xm[((size_t)(b * 256) + c2 * 2 + cl) * 25 + v] = s * (1.0f / 128.0f);
    }
}

// ---- Kernel 2: A_dyn + Afull tables + Wconv->bf16 (one block per b) [R4/R7/R9-verified] ----
__global__ __launch_bounds__(256)
void k_adyn(const float* __restrict__ xm, const float* __restrict__ A,
            const float* __restrict__ Wq, const float* __restrict__ Wk,
            const float* __restrict__ alpha, __bf16* __restrict__ afull,
            const float* __restrict__ Wconv, __bf16* __restrict__ wcb)
{
    const int b = blockIdx.x, tid = threadIdx.x;
    __shared__ float xm_s[256 * 25];
    __shared__ float q_s[64 * 25];
    __shared__ float k_s[64 * 25];
    __shared__ float sm_s[4][25][25];
    __shared__ float ad_s[25][25];
    __shared__ float rs_s[3][25];

    for (int i = tid; i < 768; i += 256)
        wcb[b * 768 + i] = (__bf16)Wconv[b * 768 + i];

    for (int i = tid; i < 256 * 25; i += 256) xm_s[i] = xm[(size_t)b * 6400 + i];
    for (int i = tid; i < 75; i += 256) {
        int k3 = i / 25, v = i - (i / 25) * 25;
        float s = 0.f;
        for (int w = 0; w < 25; ++w) s += A[(k3 * 25 + v) * 25 + w];
        rs_s[k3][v] = fmaxf(s, 1e-6f);
    }
    __syncthreads();

    for (int i = tid; i < 1600; i += 256) {
        int o = i / 25, v = i - o * 25;
        const float* wq = Wq + o * 256;
        const float* wk = Wk + o * 256;
        float aq = 0.f, ak = 0.f;
        for (int c4 = 0; c4 < 256; c4 += 4) {
            f32x4 q4 = *(const f32x4*)(wq + c4);
            f32x4 k4 = *(const f32x4*)(wk + c4);
#pragma unroll
            for (int e = 0; e < 4; ++e) {
                const float xv = xm_s[(c4 + e) * 25 + v];
                aq += q4[e] * xv;
                ak += k4[e] * xv;
            }
        }
        q_s[i] = aq; k_s[i] = ak;
    }
    __syncthreads();

    if (tid < 100) {
        int g = tid / 25, v = tid - (tid / 25) * 25;
        float l[25];
#pragma unroll
        for (int w = 0; w < 25; ++w) {
            float s = 0.f;
#pragma unroll
            for (int d = 0; d < 16; ++d)
                s += q_s[(g * 16 + d) * 25 + v] * k_s[(g * 16 + d) * 25 + w];
            l[w] = s * 0.25f;
        }
        float mx = l[0];
#pragma unroll
        for (int w = 1; w < 25; ++w) mx = fmaxf(mx, l[w]);
        float den = 0.f;
#pragma unroll
        for (int w = 0; w < 25; ++w) { l[w] = expf(l[w] - mx); den += l[w]; }
        float rden = 1.f / den;
#pragma unroll
        for (int w = 0; w < 25; ++w) sm_s[g][v][w] = l[w] * rden;
    }
    __syncthreads();
    for (int i = tid; i < 625; i += 256) {
        int v = i / 25, w = i - (i / 25) * 25;
        ad_s[v][w] = 0.25f * (sm_s[0][v][w] + sm_s[1][v][w] + sm_s[2][v][w] + sm_s[3][v][w]);
    }
    __syncthreads();

    const float al = tanhf(alpha[0]);
    for (int i = tid; i < 3 * 32 * 32; i += 256) {
        int k3 = i >> 10, rem = i & 1023, v = rem >> 5, w = rem & 31;
        float val = 0.f;
        if (v < 25 && w < 25)
            val = A[(k3 * 25 + v) * 25 + w] / rs_s[k3][v] + al * ad_s[v][w];
        afull[(size_t)b * 3072 + i] = (__bf16)val;
    }
}

// ---- Kernel 3: R9 structure (scalar staging reverted) + 5 blocks/CU ----
// ONLY changes vs R9-verified k_main7: xagg 112->100 rows (dead rows removed),
// conv remaps the never-stored cc>=100 reads to a valid row, launch_bounds(256,5).
// LDS = 16 KB + 12.8 KB = 28.8 KB -> 5 blocks/CU (was 4).
__global__ __launch_bounds__(256, 5)
void k_main9(const float* __restrict__ x, const __bf16* __restrict__ wcb,
             const __bf16* __restrict__ afull,
             const float* __restrict__ gamma, const float* __restrict__ beta,
             const float* __restrict__ rmean, const float* __restrict__ rvar,
             float* __restrict__ out)
{
    const int orig = ((blockIdx.x & 7) << 10) | (blockIdx.x >> 3);  // bijective: 8192 % 8 == 0
    const int tt = orig & 31;
    const int g  = (orig >> 5) & 3;
    const int b  = orig >> 7;
    const int tid = threadIdx.x;
    const int wave = tid >> 6;
    const int lane = tid & 63;
    const int l15 = lane & 15;
    const int lg  = lane >> 4;

    __shared__ __bf16 xs[64 * 4 * 32];     // 16 KB
    __shared__ __bf16 xagg[100 * 64];      // 12.8 KB (rows 0..99 = all valid cc)

    // ---- stage x slice -> xs (bf16, swizzled); thread = (c, t) row [R9 scalar form] ----
    {
        const int c = tid >> 2, t = tid & 3;
        const float* p = x + ((size_t)(b * 256 + g * 64 + c) * 128 + tt * 4 + t) * 25;
        float r[25];
#pragma unroll
        for (int j = 0; j < 25; ++j) r[j] = p[j];
        const int rowg = (c * 4 + t) << 2;
        const int sw = c & 7;
#pragma unroll
        for (int ch = 0; ch < 4; ++ch) {
            bf16x8 h;
#pragma unroll
            for (int e = 0; e < 8; ++e) {
                const int v = ch * 8 + e;
                h[e] = (v < 25) ? (__bf16)r[v] : (__bf16)0.f;
            }
            *(bf16x8*)((char*)xs + (((rowg | ch) ^ sw) << 4)) = h;
        }
    }

    const int o_lane = (wave << 4) + l15;
    const int ch = g * 64 + o_lane;
    const float inv  = gamma[ch] / sqrtf(rvar[ch] + 1e-5f);
    const float bias = beta[ch] - rmean[ch] * inv;

    const __bf16* ab = afull + ((size_t)(b * 3) << 10) + l15 * 32 + lg * 8;
    const __bf16* wb = wcb + (size_t)(g * 64 + o_lane) * 64 + lg * 8;

    __syncthreads();

    // ---- fragments: lane (l15, lg) reads xs[c = m*16+l15][t=wave][chunk=lg] ----
    bf16x8 xfrag[4];
#pragma unroll
    for (int m = 0; m < 4; ++m) {
        const int c = m * 16 + l15;
        xfrag[m] = *(const bf16x8*)((char*)xs +
                      (((((c * 4 + wave) << 2) | lg) ^ (c & 7)) << 4));
    }

    f32x4 acc[7];
#pragma unroll
    for (int i = 0; i < 7; ++i) acc[i] = (f32x4){0.f, 0.f, 0.f, 0.f};
    const f32x4 zero4 = {0.f, 0.f, 0.f, 0.f};

#pragma unroll
    for (int k3 = 0; k3 < 3; ++k3) {
        // per-k3 table loads (L2/L3-hot; in flight across the barrier)
        bf16x8 bA[2], wf[2];
        bA[0] = *(const bf16x8*)(ab + (size_t)k3 * 1024);
        bA[1] = *(const bf16x8*)(ab + (size_t)k3 * 1024 + 512);
        wf[0] = *(const bf16x8*)(wb + (size_t)k3 * 16384);
        wf[1] = *(const bf16x8*)(wb + (size_t)k3 * 16384 + 32);

        if (k3 > 0) __syncthreads();   // previous conv reads done before overwrite

        // aggregation: D[(t=wave, c-block m), v] -> xagg (swizzled bf16); cc = wave*25+v <= 99
#pragma unroll
        for (int m = 0; m < 4; ++m) {
#pragma unroll
            for (int n = 0; n < 2; ++n) {
                f32x4 d = __builtin_amdgcn_mfma_f32_16x16x32_bf16(xfrag[m], bA[n],
                                                                  zero4, 0, 0, 0);
                const int v = n * 16 + l15;
                if (v < 25) {
                    const int cc  = wave * 25 + v;
                    const int col = (m * 16 + lg * 4) ^ ((cc & 7) << 3);
                    bf16x4 h;
                    h[0] = (__bf16)d[0]; h[1] = (__bf16)d[1];
                    h[2] = (__bf16)d[2]; h[3] = (__bf16)d[3];
                    *(bf16x4*)((char*)xagg + cc * 128 + col * 2) = h;
                }
            }
        }
        __syncthreads();

        // conv: acc[cc-tile, o] += xagg[cc, c] * W[o, c]
        // rows cc>=100 were never written and their D rows are never stored:
        // remap those A-frag reads to row l15 (valid address, result discarded).
#pragma unroll
        for (int mcc = 0; mcc < 7; ++mcc) {
            const int cc  = mcc * 16 + l15;
            const int ccr = (cc < 100) ? cc : l15;
            const int sw2 = (ccr & 7) << 3;
#pragma unroll
            for (int ks = 0; ks < 2; ++ks) {
                const int col = (ks * 32 + lg * 8) ^ sw2;
                bf16x8 aF = *(const bf16x8*)((char*)xagg + ccr * 128 + col * 2);
                acc[mcc] = __builtin_amdgcn_mfma_f32_16x16x32_bf16(aF, wf[ks],
                                                                   acc[mcc], 0, 0, 0);
            }
        }
        if (k3 < 2) __syncthreads();
    }

    // ---- epilogue: out = x + acc*inv + bias (residual from staged bf16 xs) ----
    const size_t obase = (size_t)(b * 256 + ch) * 3200 + tt * 100;
#pragma unroll
    for (int mcc = 0; mcc < 7; ++mcc) {
        const int cc0 = mcc * 16 + lg * 4;
        if (cc0 < 100) {
            f32x4 o4;
#pragma unroll
            for (int j = 0; j < 4; ++j) {
                const int cc = cc0 + j;
                const int t = cc / 25, v = cc - t * 25;
                const int gr = (((o_lane * 4 + t) << 2) | (v >> 3)) ^ (o_lane & 7);
                const float xr = (float)*(const __bf16*)((char*)xs + (gr << 4) + ((v & 7) << 1));
                o4[j] = xr + acc[mcc][j] * inv + bias;
            }
            *(f32x4*)(out + obase + cc0) = o4;
        }
    }
}

extern "C" void kernel_launch(void* const* d_in, const int* in_sizes, int n_in,
                              void* d_out, int out_size, void* d_ws, size_t ws_size,
                              hipStream_t stream) {
    const float* x     = (const float*)d_in[0];
    const float* A     = (const float*)d_in[1];
    const float* Wq    = (const float*)d_in[2];
    const float* Wk    = (const float*)d_in[3];
    const float* Wconv = (const float*)d_in[4];
    const float* alpha = (const float*)d_in[5];
    const float* gamma = (const float*)d_in[6];
    const float* beta  = (const float*)d_in[7];
    const float* rmean = (const float*)d_in[8];
    const float* rvar  = (const float*)d_in[9];
    float* out = (float*)d_out;

    float*  xm    = (float*)d_ws;
    __bf16* afull = (__bf16*)((char*)d_ws + 1638400);
    __bf16* wcb   = (__bf16*)((char*)d_ws + 2031616);

    k_tmean4<<<64 * 128, 256, 0, stream>>>(x, xm);
    k_adyn<<<64, 256, 0, stream>>>(xm, A, Wq, Wk, alpha, afull, Wconv, wcb);
    k_main9<<<64 * 4 * 32, 256, 0, stream>>>(x, wcb, afull, gamma, beta,
                                             rmean, rvar, out);
}

// Round 12
// 198.628 us; speedup vs baseline: 1.0814x; 1.0814x over previous
//
#include <hip/hip_runtime.h>

typedef __bf16 bf16x8 __attribute__((ext_vector_type(8)));
typedef __bf16 bf16x4 __attribute__((ext_vector_type(4)));
typedef float  f32x4  __attribute__((ext_vector_type(4)));

// Shapes: B=64, C=256, T=128, V=25, K=3, G=4, Cg=64, dk=16
// ws: xm f32 @0 | afull bf16 @1,638,400 | wcb bf16 @2,031,616

// ---- Kernel 1: temporal mean, 8 channels/block (amortized reduce tail) ----
// block=(b, c8). Thread (c_loc, r) streams 4 c-pairs x 7 f32x4 coalesced loads;
// mod-25 phase arithmetic identical to R5/R9-verified k_tmean4, plus cp dim.
__global__ __launch_bounds__(256)
void k_tmean5(const float* __restrict__ x, float* __restrict__ xm)
{
    const int bid = blockIdx.x;            // b*32 + c8
    const int b = bid >> 5, c8 = bid & 31;
    const int tid = threadIdx.x;
    const int c_loc = tid >> 7, r = tid & 127;

    __shared__ float xpart[4][2][25][5][4];   // 16 KB

    if (r < 125) {
        const int vq = r % 25, jg = r / 25;
#pragma unroll
        for (int cp = 0; cp < 4; ++cp) {
            const int c = c8 * 8 + cp * 2 + c_loc;
            const float* base = x + (size_t)(b * 256 + c) * 3200;
            f32x4 acc = {0.f, 0.f, 0.f, 0.f};
#pragma unroll
            for (int i = 0; i < 7; ++i) {
                const int q = r + 125 * i;
                if (q < 800) {
                    f32x4 v4 = *(const f32x4*)(base + q * 4);   // 16B-aligned
                    acc += v4;
                }
            }
            *(f32x4*)(&xpart[cp][c_loc][vq][jg][0]) = acc;
        }
    }
    __syncthreads();
    if (tid < 200) {
        const int cp = tid / 50, rem = tid - cp * 50;
        const int cl = rem / 25, v = rem - cl * 25;
        float s = 0.f;
#pragma unroll
        for (int e = 0; e < 4; ++e) {
            const int vq = (((v - e + 25) % 25) * 19) % 25;  // 4*vq == v-e (mod 25)
#pragma unroll
            for (int j = 0; j < 5; ++j) s += xpart[cp][cl][vq][j][e];
        }
        xm[((size_t)(b * 256) + c8 * 8 + cp * 2 + cl) * 25 + v] = s * (1.0f / 128.0f);
    }
}

// ---- Kernel 2: A_dyn + Afull tables + Wconv->bf16 (one block per b) [R4/R7/R9-verified] ----
__global__ __launch_bounds__(256)
void k_adyn(const float* __restrict__ xm, const float* __restrict__ A,
            const float* __restrict__ Wq, const float* __restrict__ Wk,
            const float* __restrict__ alpha, __bf16* __restrict__ afull,
            const float* __restrict__ Wconv, __bf16* __restrict__ wcb)
{
    const int b = blockIdx.x, tid = threadIdx.x;
    __shared__ float xm_s[256 * 25];
    __shared__ float q_s[64 * 25];
    __shared__ float k_s[64 * 25];
    __shared__ float sm_s[4][25][25];
    __shared__ float ad_s[25][25];
    __shared__ float rs_s[3][25];

    for (int i = tid; i < 768; i += 256)
        wcb[b * 768 + i] = (__bf16)Wconv[b * 768 + i];

    for (int i = tid; i < 256 * 25; i += 256) xm_s[i] = xm[(size_t)b * 6400 + i];
    for (int i = tid; i < 75; i += 256) {
        int k3 = i / 25, v = i - (i / 25) * 25;
        float s = 0.f;
        for (int w = 0; w < 25; ++w) s += A[(k3 * 25 + v) * 25 + w];
        rs_s[k3][v] = fmaxf(s, 1e-6f);
    }
    __syncthreads();

    for (int i = tid; i < 1600; i += 256) {
        int o = i / 25, v = i - o * 25;
        const float* wq = Wq + o * 256;
        const float* wk = Wk + o * 256;
        float aq = 0.f, ak = 0.f;
        for (int c4 = 0; c4 < 256; c4 += 4) {
            f32x4 q4 = *(const f32x4*)(wq + c4);
            f32x4 k4 = *(const f32x4*)(wk + c4);
#pragma unroll
            for (int e = 0; e < 4; ++e) {
                const float xv = xm_s[(c4 + e) * 25 + v];
                aq += q4[e] * xv;
                ak += k4[e] * xv;
            }
        }
        q_s[i] = aq; k_s[i] = ak;
    }
    __syncthreads();

    if (tid < 100) {
        int g = tid / 25, v = tid - (tid / 25) * 25;
        float l[25];
#pragma unroll
        for (int w = 0; w < 25; ++w) {
            float s = 0.f;
#pragma unroll
            for (int d = 0; d < 16; ++d)
                s += q_s[(g * 16 + d) * 25 + v] * k_s[(g * 16 + d) * 25 + w];
            l[w] = s * 0.25f;
        }
        float mx = l[0];
#pragma unroll
        for (int w = 1; w < 25; ++w) mx = fmaxf(mx, l[w]);
        float den = 0.f;
#pragma unroll
        for (int w = 0; w < 25; ++w) { l[w] = expf(l[w] - mx); den += l[w]; }
        float rden = 1.f / den;
#pragma unroll
        for (int w = 0; w < 25; ++w) sm_s[g][v][w] = l[w] * rden;
    }
    __syncthreads();
    for (int i = tid; i < 625; i += 256) {
        int v = i / 25, w = i - (i / 25) * 25;
        ad_s[v][w] = 0.25f * (sm_s[0][v][w] + sm_s[1][v][w] + sm_s[2][v][w] + sm_s[3][v][w]);
    }
    __syncthreads();

    const float al = tanhf(alpha[0]);
    for (int i = tid; i < 3 * 32 * 32; i += 256) {
        int k3 = i >> 10, rem = i & 1023, v = rem >> 5, w = rem & 31;
        float val = 0.f;
        if (v < 25 && w < 25)
            val = A[(k3 * 25 + v) * 25 + w] / rs_s[k3][v] + al * ad_s[v][w];
        afull[(size_t)b * 3072 + i] = (__bf16)val;
    }
}

// ---- Kernel 3: R9-verified k_main7 (exact revert: 112-row xagg, (256,4), scalar staging) ----
__global__ __launch_bounds__(256, 4)
void k_main7(const float* __restrict__ x, const __bf16* __restrict__ wcb,
             const __bf16* __restrict__ afull,
             const float* __restrict__ gamma, const float* __restrict__ beta,
             const float* __restrict__ rmean, const float* __restrict__ rvar,
             float* __restrict__ out)
{
    const int orig = ((blockIdx.x & 7) << 10) | (blockIdx.x >> 3);  // bijective: 8192 % 8 == 0
    const int tt = orig & 31;
    const int g  = (orig >> 5) & 3;
    const int b  = orig >> 7;
    const int tid = threadIdx.x;
    const int wave = tid >> 6;
    const int lane = tid & 63;
    const int l15 = lane & 15;
    const int lg  = lane >> 4;

    __shared__ __bf16 xs[64 * 4 * 32];     // 16 KB
    __shared__ __bf16 xagg[112 * 64];      // 14.3 KB

    // ---- stage x slice -> xs (bf16, swizzled); thread = (c, t) row ----
    {
        const int c = tid >> 2, t = tid & 3;
        const float* p = x + ((size_t)(b * 256 + g * 64 + c) * 128 + tt * 4 + t) * 25;
        float r[25];
#pragma unroll
        for (int j = 0; j < 25; ++j) r[j] = p[j];
        const int rowg = (c * 4 + t) << 2;
        const int sw = c & 7;
#pragma unroll
        for (int ch = 0; ch < 4; ++ch) {
            bf16x8 h;
#pragma unroll
            for (int e = 0; e < 8; ++e) {
                const int v = ch * 8 + e;
                h[e] = (v < 25) ? (__bf16)r[v] : (__bf16)0.f;
            }
            *(bf16x8*)((char*)xs + (((rowg | ch) ^ sw) << 4)) = h;
        }
    }

    const int o_lane = (wave << 4) + l15;
    const int ch = g * 64 + o_lane;
    const float inv  = gamma[ch] / sqrtf(rvar[ch] + 1e-5f);
    const float bias = beta[ch] - rmean[ch] * inv;

    const __bf16* ab = afull + ((size_t)(b * 3) << 10) + l15 * 32 + lg * 8;
    const __bf16* wb = wcb + (size_t)(g * 64 + o_lane) * 64 + lg * 8;

    __syncthreads();

    // ---- fragments: lane (l15, lg) reads xs[c = m*16+l15][t=wave][chunk=lg] ----
    bf16x8 xfrag[4];
#pragma unroll
    for (int m = 0; m < 4; ++m) {
        const int c = m * 16 + l15;
        xfrag[m] = *(const bf16x8*)((char*)xs +
                      (((((c * 4 + wave) << 2) | lg) ^ (c & 7)) << 4));
    }

    f32x4 acc[7];
#pragma unroll
    for (int i = 0; i < 7; ++i) acc[i] = (f32x4){0.f, 0.f, 0.f, 0.f};
    const f32x4 zero4 = {0.f, 0.f, 0.f, 0.f};

#pragma unroll
    for (int k3 = 0; k3 < 3; ++k3) {
        // per-k3 table loads (L2/L3-hot; in flight across the barrier)
        bf16x8 bA[2], wf[2];
        bA[0] = *(const bf16x8*)(ab + (size_t)k3 * 1024);
        bA[1] = *(const bf16x8*)(ab + (size_t)k3 * 1024 + 512);
        wf[0] = *(const bf16x8*)(wb + (size_t)k3 * 16384);
        wf[1] = *(const bf16x8*)(wb + (size_t)k3 * 16384 + 32);

        if (k3 > 0) __syncthreads();   // previous conv reads done before overwrite

        // aggregation: D[(t=wave, c-block m), v] -> xagg (swizzled bf16)
#pragma unroll
        for (int m = 0; m < 4; ++m) {
#pragma unroll
            for (int n = 0; n < 2; ++n) {
                f32x4 d = __builtin_amdgcn_mfma_f32_16x16x32_bf16(xfrag[m], bA[n],
                                                                  zero4, 0, 0, 0);
                const int v = n * 16 + l15;
                if (v < 25) {
                    const int cc  = wave * 25 + v;
                    const int col = (m * 16 + lg * 4) ^ ((cc & 7) << 3);
                    bf16x4 h;
                    h[0] = (__bf16)d[0]; h[1] = (__bf16)d[1];
                    h[2] = (__bf16)d[2]; h[3] = (__bf16)d[3];
                    *(bf16x4*)((char*)xagg + cc * 128 + col * 2) = h;
                }
            }
        }
        __syncthreads();

        // conv: acc[cc-tile, o] += xagg[cc, c] * W[o, c]
#pragma unroll
        for (int mcc = 0; mcc < 7; ++mcc) {
            const int cc = mcc * 16 + l15;
            const int sw2 = (cc & 7) << 3;
#pragma unroll
            for (int ks = 0; ks < 2; ++ks) {
                const int col = (ks * 32 + lg * 8) ^ sw2;
                bf16x8 aF = *(const bf16x8*)((char*)xagg + cc * 128 + col * 2);
                acc[mcc] = __builtin_amdgcn_mfma_f32_16x16x32_bf16(aF, wf[ks],
                                                                   acc[mcc], 0, 0, 0);
            }
        }
        if (k3 < 2) __syncthreads();
    }

    // ---- epilogue: out = x + acc*inv + bias (residual from staged bf16 xs) ----
    const size_t obase = (size_t)(b * 256 + ch) * 3200 + tt * 100;
#pragma unroll
    for (int mcc = 0; mcc < 7; ++mcc) {
        const int cc0 = mcc * 16 + lg * 4;
        if (cc0 < 100) {
            f32x4 o4;
#pragma unroll
            for (int j = 0; j < 4; ++j) {
                const int cc = cc0 + j;
                const int t = cc / 25, v = cc - t * 25;
                const int gr = (((o_lane * 4 + t) << 2) | (v >> 3)) ^ (o_lane & 7);
                const float xr = (float)*(const __bf16*)((char*)xs + (gr << 4) + ((v & 7) << 1));
                o4[j] = xr + acc[mcc][j] * inv + bias;
            }
            *(f32x4*)(out + obase + cc0) = o4;
        }
    }
}

extern "C" void kernel_launch(void* const* d_in, const int* in_sizes, int n_in,
                              void* d_out, int out_size, void* d_ws, size_t ws_size,
                              hipStream_t stream) {
    const float* x     = (const float*)d_in[0];
    const float* A     = (const float*)d_in[1];
    const float* Wq    = (const float*)d_in[2];
    const float* Wk    = (const float*)d_in[3];
    const float* Wconv = (const float*)d_in[4];
    const float* alpha = (const float*)d_in[5];
    const float* gamma = (const float*)d_in[6];
    const float* beta  = (const float*)d_in[7];
    const float* rmean = (const float*)d_in[8];
    const float* rvar  = (const float*)d_in[9];
    float* out = (float*)d_out;

    float*  xm    = (float*)d_ws;
    __bf16* afull = (__bf16*)((char*)d_ws + 1638400);
    __bf16* wcb   = (__bf16*)((char*)d_ws + 2031616);

    k_tmean5<<<64 * 32, 256, 0, stream>>>(x, xm);
    k_adyn<<<64, 256, 0, stream>>>(xm, A, Wq, Wk, alpha, afull, Wconv, wcb);
    k_main7<<<64 * 4 * 32, 256, 0, stream>>>(x, wcb, afull, gamma, beta,
                                             rmean, rvar, out);
}

// Round 13
// 196.634 us; speedup vs baseline: 1.0924x; 1.0101x over previous
//
#include <hip/hip_runtime.h>

typedef __bf16 bf16x8 __attribute__((ext_vector_type(8)));
typedef __bf16 bf16x4 __attribute__((ext_vector_type(4)));
typedef float  f32x4  __attribute__((ext_vector_type(4)));

// Shapes: B=64, C=256, T=128, V=25, K=3, G=4, Cg=64, dk=16
// ws: xm f32 @0 | afull bf16 @1,638,400 | wcb bf16 @2,031,616

// ---- Kernel 1: temporal mean (pure stream, deterministic tree-sum) [R5/R7/R9-verified] ----
__global__ __launch_bounds__(256)
void k_tmean4(const float* __restrict__ x, float* __restrict__ xm)
{
    const int bid = blockIdx.x;            // b*128 + c2
    const int b = bid >> 7, c2 = bid & 127;
    const int tid = threadIdx.x;
    const int c_loc = tid >> 7, r = tid & 127;

    __shared__ float xpart[2][25][5][4];   // 4 KB

    if (r < 125) {
        const float* base = x + (size_t)(b * 256 + c2 * 2 + c_loc) * 3200;
        f32x4 acc = {0.f, 0.f, 0.f, 0.f};
#pragma unroll
        for (int i = 0; i < 7; ++i) {
            const int q = r + 125 * i;
            if (q < 800) {
                f32x4 v4 = *(const f32x4*)(base + q * 4);   // 16B-aligned
                acc += v4;
            }
        }
        const int vq = r % 25, jg = r / 25;
        *(f32x4*)(&xpart[c_loc][vq][jg][0]) = acc;
    }
    __syncthreads();
    if (tid < 50) {
        const int cl = tid / 25, v = tid - cl * 25;
        float s = 0.f;
#pragma unroll
        for (int e = 0; e < 4; ++e) {
            const int vq = (((v - e + 25) % 25) * 19) % 25;  // 4*vq == v-e (mod 25)
#pragma unroll
            for (int j = 0; j < 5; ++j) s += xpart[cl][vq][j][e];
        }
        xm[((size_t)(b * 256) + c2 * 2 + cl) * 25 + v] = s * (1.0f / 128.0f);
    }
}

// ---- Kernel 2: A_dyn + Afull tables + Wconv->bf16 (one block per b) [R4/R7/R9-verified] ----
__global__ __launch_bounds__(256)
void k_adyn(const float* __restrict__ xm, const float* __restrict__ A,
            const float* __restrict__ Wq, const float* __restrict__ Wk,
            const float* __restrict__ alpha, __bf16* __restrict__ afull,
            const float* __restrict__ Wconv, __bf16* __restrict__ wcb)
{
    const int b = blockIdx.x, tid = threadIdx.x;
    __shared__ float xm_s[256 * 25];
    __shared__ float q_s[64 * 25];
    __shared__ float k_s[64 * 25];
    __shared__ float sm_s[4][25][25];
    __shared__ float ad_s[25][25];
    __shared__ float rs_s[3][25];

    for (int i = tid; i < 768; i += 256)
        wcb[b * 768 + i] = (__bf16)Wconv[b * 768 + i];

    for (int i = tid; i < 256 * 25; i += 256) xm_s[i] = xm[(size_t)b * 6400 + i];
    for (int i = tid; i < 75; i += 256) {
        int k3 = i / 25, v = i - (i / 25) * 25;
        float s = 0.f;
        for (int w = 0; w < 25; ++w) s += A[(k3 * 25 + v) * 25 + w];
        rs_s[k3][v] = fmaxf(s, 1e-6f);
    }
    __syncthreads();

    for (int i = tid; i < 1600; i += 256) {
        int o = i / 25, v = i - o * 25;
        const float* wq = Wq + o * 256;
        const float* wk = Wk + o * 256;
        float aq = 0.f, ak = 0.f;
        for (int c4 = 0; c4 < 256; c4 += 4) {
            f32x4 q4 = *(const f32x4*)(wq + c4);
            f32x4 k4 = *(const f32x4*)(wk + c4);
#pragma unroll
            for (int e = 0; e < 4; ++e) {
                const float xv = xm_s[(c4 + e) * 25 + v];
                aq += q4[e] * xv;
                ak += k4[e] * xv;
            }
        }
        q_s[i] = aq; k_s[i] = ak;
    }
    __syncthreads();

    if (tid < 100) {
        int g = tid / 25, v = tid - (tid / 25) * 25;
        float l[25];
#pragma unroll
        for (int w = 0; w < 25; ++w) {
            float s = 0.f;
#pragma unroll
            for (int d = 0; d < 16; ++d)
                s += q_s[(g * 16 + d) * 25 + v] * k_s[(g * 16 + d) * 25 + w];
            l[w] = s * 0.25f;
        }
        float mx = l[0];
#pragma unroll
        for (int w = 1; w < 25; ++w) mx = fmaxf(mx, l[w]);
        float den = 0.f;
#pragma unroll
        for (int w = 0; w < 25; ++w) { l[w] = expf(l[w] - mx); den += l[w]; }
        float rden = 1.f / den;
#pragma unroll
        for (int w = 0; w < 25; ++w) sm_s[g][v][w] = l[w] * rden;
    }
    __syncthreads();
    for (int i = tid; i < 625; i += 256) {
        int v = i / 25, w = i - (i / 25) * 25;
        ad_s[v][w] = 0.25f * (sm_s[0][v][w] + sm_s[1][v][w] + sm_s[2][v][w] + sm_s[3][v][w]);
    }
    __syncthreads();

    const float al = tanhf(alpha[0]);
    for (int i = tid; i < 3 * 32 * 32; i += 256) {
        int k3 = i >> 10, rem = i & 1023, v = rem >> 5, w = rem & 31;
        float val = 0.f;
        if (v < 25 && w < 25)
            val = A[(k3 * 25 + v) * 25 + w] / rs_s[k3][v] + al * ad_s[v][w];
        afull[(size_t)b * 3072 + i] = (__bf16)val;
    }
}

// ---- Kernel 3: R9 k_main7 + xagg-100 (R11-verified) at (256,4): 5th block fits by HW limit ----
// LDS = 16 KB + 12.8 KB = 29184 B -> 5 blocks/CU; VGPR stays 64 (no regalloc squeeze).
__global__ __launch_bounds__(256, 4)
void k_main10(const float* __restrict__ x, const __bf16* __restrict__ wcb,
              const __bf16* __restrict__ afull,
              const float* __restrict__ gamma, const float* __restrict__ beta,
              const float* __restrict__ rmean, const float* __restrict__ rvar,
              float* __restrict__ out)
{
    const int orig = ((blockIdx.x & 7) << 10) | (blockIdx.x >> 3);  // bijective: 8192 % 8 == 0
    const int tt = orig & 31;
    const int g  = (orig >> 5) & 3;
    const int b  = orig >> 7;
    const int tid = threadIdx.x;
    const int wave = tid >> 6;
    const int lane = tid & 63;
    const int l15 = lane & 15;
    const int lg  = lane >> 4;

    __shared__ __bf16 xs[64 * 4 * 32];     // 16 KB
    __shared__ __bf16 xagg[100 * 64];      // 12.8 KB (rows 0..99 = all valid cc)

    // ---- stage x slice -> xs (bf16, swizzled); thread = (c, t) row [R9 scalar form] ----
    {
        const int c = tid >> 2, t = tid & 3;
        const float* p = x + ((size_t)(b * 256 + g * 64 + c) * 128 + tt * 4 + t) * 25;
        float r[25];
#pragma unroll
        for (int j = 0; j < 25; ++j) r[j] = p[j];
        const int rowg = (c * 4 + t) << 2;
        const int sw = c & 7;
#pragma unroll
        for (int ch = 0; ch < 4; ++ch) {
            bf16x8 h;
#pragma unroll
            for (int e = 0; e < 8; ++e) {
                const int v = ch * 8 + e;
                h[e] = (v < 25) ? (__bf16)r[v] : (__bf16)0.f;
            }
            *(bf16x8*)((char*)xs + (((rowg | ch) ^ sw) << 4)) = h;
        }
    }

    const int o_lane = (wave << 4) + l15;
    const int ch = g * 64 + o_lane;
    const float inv  = gamma[ch] / sqrtf(rvar[ch] + 1e-5f);
    const float bias = beta[ch] - rmean[ch] * inv;

    const __bf16* ab = afull + ((size_t)(b * 3) << 10) + l15 * 32 + lg * 8;
    const __bf16* wb = wcb + (size_t)(g * 64 + o_lane) * 64 + lg * 8;

    __syncthreads();

    // ---- fragments: lane (l15, lg) reads xs[c = m*16+l15][t=wave][chunk=lg] ----
    bf16x8 xfrag[4];
#pragma unroll
    for (int m = 0; m < 4; ++m) {
        const int c = m * 16 + l15;
        xfrag[m] = *(const bf16x8*)((char*)xs +
                      (((((c * 4 + wave) << 2) | lg) ^ (c & 7)) << 4));
    }

    f32x4 acc[7];
#pragma unroll
    for (int i = 0; i < 7; ++i) acc[i] = (f32x4){0.f, 0.f, 0.f, 0.f};
    const f32x4 zero4 = {0.f, 0.f, 0.f, 0.f};

#pragma unroll
    for (int k3 = 0; k3 < 3; ++k3) {
        // per-k3 table loads (L2/L3-hot; in flight across the barrier)
        bf16x8 bA[2], wf[2];
        bA[0] = *(const bf16x8*)(ab + (size_t)k3 * 1024);
        bA[1] = *(const bf16x8*)(ab + (size_t)k3 * 1024 + 512);
        wf[0] = *(const bf16x8*)(wb + (size_t)k3 * 16384);
        wf[1] = *(const bf16x8*)(wb + (size_t)k3 * 16384 + 32);

        if (k3 > 0) __syncthreads();   // previous conv reads done before overwrite

        // aggregation: D[(t=wave, c-block m), v] -> xagg (swizzled bf16); cc = wave*25+v <= 99
#pragma unroll
        for (int m = 0; m < 4; ++m) {
#pragma unroll
            for (int n = 0; n < 2; ++n) {
                f32x4 d = __builtin_amdgcn_mfma_f32_16x16x32_bf16(xfrag[m], bA[n],
                                                                  zero4, 0, 0, 0);
                const int v = n * 16 + l15;
                if (v < 25) {
                    const int cc  = wave * 25 + v;
                    const int col = (m * 16 + lg * 4) ^ ((cc & 7) << 3);
                    bf16x4 h;
                    h[0] = (__bf16)d[0]; h[1] = (__bf16)d[1];
                    h[2] = (__bf16)d[2]; h[3] = (__bf16)d[3];
                    *(bf16x4*)((char*)xagg + cc * 128 + col * 2) = h;
                }
            }
        }
        __syncthreads();

        // conv: acc[cc-tile, o] += xagg[cc, c] * W[o, c]
        // rows cc>=100 never written & their D rows never stored -> remap reads to row l15
        // (valid address, result discarded). [R11-verified]
#pragma unroll
        for (int mcc = 0; mcc < 7; ++mcc) {
            const int cc  = mcc * 16 + l15;
            const int ccr = (cc < 100) ? cc : l15;
            const int sw2 = (ccr & 7) << 3;
#pragma unroll
            for (int ks = 0; ks < 2; ++ks) {
                const int col = (ks * 32 + lg * 8) ^ sw2;
                bf16x8 aF = *(const bf16x8*)((char*)xagg + ccr * 128 + col * 2);
                acc[mcc] = __builtin_amdgcn_mfma_f32_16x16x32_bf16(aF, wf[ks],
                                                                   acc[mcc], 0, 0, 0);
            }
        }
        if (k3 < 2) __syncthreads();
    }

    // ---- epilogue: out = x + acc*inv + bias (residual from staged bf16 xs) ----
    const size_t obase = (size_t)(b * 256 + ch) * 3200 + tt * 100;
#pragma unroll
    for (int mcc = 0; mcc < 7; ++mcc) {
        const int cc0 = mcc * 16 + lg * 4;
        if (cc0 < 100) {
            f32x4 o4;
#pragma unroll
            for (int j = 0; j < 4; ++j) {
                const int cc = cc0 + j;
                const int t = cc / 25, v = cc - t * 25;
                const int gr = (((o_lane * 4 + t) << 2) | (v >> 3)) ^ (o_lane & 7);
                const float xr = (float)*(const __bf16*)((char*)xs + (gr << 4) + ((v & 7) << 1));
                o4[j] = xr + acc[mcc][j] * inv + bias;
            }
            *(f32x4*)(out + obase + cc0) = o4;
        }
    }
}

extern "C" void kernel_launch(void* const* d_in, const int* in_sizes, int n_in,
                              void* d_out, int out_size, void* d_ws, size_t ws_size,
                              hipStream_t stream) {
    const float* x     = (const float*)d_in[0];
    const float* A     = (const float*)d_in[1];
    const float* Wq    = (const float*)d_in[2];
    const float* Wk    = (const float*)d_in[3];
    const float* Wconv = (const float*)d_in[4];
    const float* alpha = (const float*)d_in[5];
    const float* gamma = (const float*)d_in[6];
    const float* beta  = (const float*)d_in[7];
    const float* rmean = (const float*)d_in[8];
    const float* rvar  = (const float*)d_in[9];
    float* out = (float*)d_out;

    float*  xm    = (float*)d_ws;
    __bf16* afull = (__bf16*)((char*)d_ws + 1638400);
    __bf16* wcb   = (__bf16*)((char*)d_ws + 2031616);

    k_tmean4<<<64 * 128, 256, 0, stream>>>(x, xm);
    k_adyn<<<64, 256, 0, stream>>>(xm, A, Wq, Wk, alpha, afull, Wconv, wcb);
    k_main10<<<64 * 4 * 32, 256, 0, stream>>>(x, wcb, afull, gamma, beta,
                                              rmean, rvar, out);
}